// Round 1
// baseline (308.749 us; speedup 1.0000x reference)
//
#include <hip/hip_runtime.h>

// minLSTM fused kernel for MI355X.
// Math: log-space scan == linear recurrence h_t = f_t*h_{t-1} + i_t*g(hidden_t)
//   f = (1+e^{-ig_gate... }) see below; contractive (f in (0,1)), bounded -> fp32 safe.
// Layout: 1 block per (b,g): 4 waves x 64 lanes x 4 timesteps = 1024 s per iter, 8 iters.
//   Wave-level affine-pair (P,Q) shuffle scan; cross-wave carry via LDS aggregates.

constexpr int Bc = 4, Sc = 8192, Dc = 1024, Hc = 1024;
constexpr int WAVES = 4;
constexpr int BLOCK = WAVES * 64;   // 256
constexpr int KPL = 4;              // consecutive timesteps per lane
constexpr int SPW = 64 * KPL;       // 256 s per wave per iter
constexpr int SPI = WAVES * SPW;    // 1024 s per block per iter
constexpr int NIT = Sc / SPI;       // 8

__device__ __forceinline__ float frcp(float v) { return __builtin_amdgcn_rcpf(v); }

__global__ __launch_bounds__(BLOCK, 4)
void minlstm_kernel(const float* __restrict__ x,
                    const float* __restrict__ Wf,
                    const float* __restrict__ Wi,
                    const float* __restrict__ Wh,
                    float* __restrict__ out)
{
    // XCD-aware remap: put the 4 groups sharing each 128B line on the same XCD.
    const int blk = blockIdx.x;           // 0..511
    const int xcd = blk & 7;
    const int j   = blk >> 3;             // 0..63
    const int q   = xcd * 4 + (j >> 4);   // group-quad 0..31
    const int rem = j & 15;
    const int b   = rem >> 2;             // 0..3
    const int r   = rem & 3;              // 0..3
    const int g   = q * 4 + r;            // 0..127

    const int tid  = threadIdx.x;
    const int lane = tid & 63;
    const int w    = tid >> 6;

    __shared__ float aggP[2][2][4][WAVES];   // [buf][half][o_sub][wave]
    __shared__ float aggQ[2][2][4][WAVES];

    const float* __restrict__ wfg = Wf + g * 64;   // (8 out x 8 in), block-uniform
    const float* __restrict__ wig = Wi + g * 64;
    const float* __restrict__ whg = Wh + g * 64;

    float carry[8];
#pragma unroll
    for (int o = 0; o < 8; ++o) carry[o] = 0.f;

    for (int it = 0; it < NIT; ++it) {
        const int s0 = it * SPI + w * SPW + lane * KPL;   // lane's first row
        const float* xp = x + ((size_t)(b * Sc + s0) * Dc + g * 8);
        float4 xv[KPL][2];
#pragma unroll
        for (int k = 0; k < KPL; ++k) {
            xv[k][0] = *(const float4*)(xp + (size_t)k * Dc);
            xv[k][1] = *(const float4*)(xp + (size_t)k * Dc + 4);
        }
        const int buf = it & 1;

#pragma unroll
        for (int half = 0; half < 2; ++half) {
            float aa[4][KPL], vv[4][KPL];   // per-element (a,v) kept for apply phase
            float Pe[4], Qe[4];             // lane-exclusive prefix per channel
#pragma unroll
            for (int os = 0; os < 4; ++os) {
                const int o = half * 4 + os;
                float P = 1.f, Q = 0.f;
#pragma unroll
                for (int k = 0; k < KPL; ++k) {
                    const float* xk = (const float*)&xv[k][0];
                    float fg = 0.f, ig = 0.f, hh = 0.f;
#pragma unroll
                    for (int ii = 0; ii < 8; ++ii) {
                        const float xi = xk[ii];
                        fg = fmaf(xi, wfg[o * 8 + ii], fg);
                        ig = fmaf(xi, wig[o * 8 + ii], ig);
                        hh = fmaf(xi, whg[o * 8 + ii], hh);
                    }
                    // f = sigmoid(-diff), i = sigmoid(diff),
                    // e^diff = (1+e^-fg)/(1+e^-ig)  =>  closed form below.
                    const float Ef   = __expf(-fg);
                    const float Ei   = __expf(-ig);
                    const float rden = frcp(2.f + Ef + Ei);
                    const float a    = (1.f + Ei) * rden;      // forget coeff
                    const float ic   = (1.f + Ef) * rden;      // input coeff
                    const float gg   = (hh >= 0.f) ? (hh + 0.5f)
                                                   : frcp(1.f + __expf(-hh));
                    const float v    = ic * gg;
                    aa[os][k] = a;
                    vv[os][k] = v;
                    Q = fmaf(a, Q, v);     // serial compose over lane's 4 steps
                    P = a * P;
                }
                // wave-wide inclusive scan of affine pairs (lower lanes = earlier s)
#pragma unroll
                for (int d = 1; d < 64; d <<= 1) {
                    float Pp = __shfl_up(P, (unsigned)d, 64);
                    float Qp = __shfl_up(Q, (unsigned)d, 64);
                    const bool val = (lane >= d);
                    Pp = val ? Pp : 1.f;
                    Qp = val ? Qp : 0.f;
                    Q = fmaf(P, Qp, Q);
                    P = P * Pp;
                }
                float Pex = __shfl_up(P, 1u, 64);
                float Qex = __shfl_up(Q, 1u, 64);
                if (lane == 0) { Pex = 1.f; Qex = 0.f; }
                Pe[os] = Pex; Qe[os] = Qex;
                if (lane == 63) {           // wave aggregate
                    aggP[buf][half][os][w] = P;
                    aggQ[buf][half][os][w] = Q;
                }
            }
            __syncthreads();
            // redundant cross-wave combine (uniform, cheap); all waves track carry
            float hin[4];
#pragma unroll
            for (int os = 0; os < 4; ++os) {
                float h = carry[half * 4 + os];
                float myin = h;
#pragma unroll
                for (int wp = 0; wp < WAVES; ++wp) {
                    myin = (wp == w) ? h : myin;
                    h = fmaf(aggP[buf][half][os][wp], h, aggQ[buf][half][os][wp]);
                }
                carry[half * 4 + os] = h;
                hin[os] = myin;
            }
            // apply: h at lane start, then serial through the 4 kept (a,v)
            float hstg[KPL][4];
#pragma unroll
            for (int os = 0; os < 4; ++os) {
                float hp = fmaf(Pe[os], hin[os], Qe[os]);
#pragma unroll
                for (int k = 0; k < KPL; ++k) {
                    hp = fmaf(aa[os][k], hp, vv[os][k]);
                    hstg[k][os] = hp;
                }
            }
#pragma unroll
            for (int k = 0; k < KPL; ++k) {
                float4 o4 = make_float4(hstg[k][0], hstg[k][1], hstg[k][2], hstg[k][3]);
                *(float4*)(out + (size_t)(b * Sc + s0 + k) * Hc + g * 8 + half * 4) = o4;
            }
        }
    }
}

extern "C" void kernel_launch(void* const* d_in, const int* in_sizes, int n_in,
                              void* d_out, int out_size, void* d_ws, size_t ws_size,
                              hipStream_t stream) {
    (void)in_sizes; (void)n_in; (void)d_ws; (void)ws_size; (void)out_size;
    const float* x  = (const float*)d_in[0];
    const float* Wf = (const float*)d_in[1];
    const float* Wi = (const float*)d_in[2];
    const float* Wh = (const float*)d_in[3];
    float* out = (float*)d_out;
    minlstm_kernel<<<dim3(512), dim3(BLOCK), 0, stream>>>(x, Wf, Wi, Wh, out);
}